// Round 6
// baseline (562.243 us; speedup 1.0000x reference)
//
#include <hip/hip_runtime.h>
#include <cmath>

#define BATCH 256
#define PAIRS 90
#define NPAIR (BATCH * PAIRS)
#define CV 1024

// K1: one block (256 thr = 4 waves) per pair (b,p). Wave w handles image-row
// stripes 2w and 2w+1 (8 rows = one fx group each). Window max via in-wave
// shuffles — no LDS atomics. Lane l's two float4 per stripe (i=l, i=l+64)
// share window col c=(l&15)>>1; lanes sharing c differ only in bits {0,4,5},
// so xor-reduce over masks {1,16,32} completes each 8x8 window max.
__global__ __launch_bounds__(256) void pool_score_kernel(
    const float* __restrict__ feat, const float* __restrict__ w_att,
    const float* __restrict__ b_att, float* __restrict__ pooled,
    float* __restrict__ scores)
{
    const int pair = blockIdx.x;
    const float4* __restrict__ src = (const float4*)(feat + (size_t)pair * 4096);
    __shared__ float smax[64];
    const int t = threadIdx.x;
    const int w = t >> 6, l = t & 63;

    const int base = w * 256 + l;          // float4 index in 64x64 tile
    const float4 a0 = src[base];           // stripe 2w,   i = l
    const float4 a1 = src[base + 64];      // stripe 2w,   i = l+64
    const float4 b0 = src[base + 128];     // stripe 2w+1, i = l
    const float4 b1 = src[base + 192];     // stripe 2w+1, i = l+64
    float ma = fmaxf(fmaxf(fmaxf(a0.x, a0.y), fmaxf(a0.z, a0.w)),
                     fmaxf(fmaxf(a1.x, a1.y), fmaxf(a1.z, a1.w)));
    float mb = fmaxf(fmaxf(fmaxf(b0.x, b0.y), fmaxf(b0.z, b0.w)),
                     fmaxf(fmaxf(b1.x, b1.y), fmaxf(b1.z, b1.w)));

    ma = fmaxf(ma, __shfl_xor(ma, 1, 64));
    mb = fmaxf(mb, __shfl_xor(mb, 1, 64));
    ma = fmaxf(ma, __shfl_xor(ma, 16, 64));
    mb = fmaxf(mb, __shfl_xor(mb, 16, 64));
    ma = fmaxf(ma, __shfl_xor(ma, 32, 64));
    mb = fmaxf(mb, __shfl_xor(mb, 32, 64));

    if ((l & 0x31) == 0) {                 // bits 0,4,5 clear: l in {0,2,..,14}
        const int c = l >> 1;              // window col (fy)
        smax[(2 * w) * 8 + c]     = ma;    // fx = stripe index
        smax[(2 * w + 1) * 8 + c] = mb;
    }
    __syncthreads();
    if (t < 64) {                          // wave 0 exactly
        const float v = smax[t];
        pooled[(size_t)pair * 64 + t] = v;
        float part = v * w_att[t];
#pragma unroll
        for (int off = 32; off > 0; off >>= 1)
            part += __shfl_xor(part, off, 64);
        if (t == 0) scores[pair] = part + b_att[0];
    }
}

// K2: per batch top-k (k from device scalar), lowest-index tie-break (matches
// jax.lax.top_k). scale[b,p] = score if selected else 0.
__global__ __launch_bounds__(64) void topk_kernel(
    const float* __restrict__ scores, const int* __restrict__ kp,
    float* __restrict__ scale)
{
    const int b = blockIdx.x;
    const int l = threadIdx.x;       // one wave
    const int k = *kp;
    const int i0 = l, i1 = l + 64;
    const float s0 = (i0 < PAIRS) ? scores[b * PAIRS + i0] : -INFINITY;
    const float s1 = (i1 < PAIRS) ? scores[b * PAIRS + i1] : -INFINITY;
    float v0 = s0, v1 = s1;
    bool sel0 = false, sel1 = false;
    for (int it = 0; it < k && it < PAIRS; ++it) {
        float mv; int mi;
        if (v0 >= v1) { mv = v0; mi = i0; } else { mv = v1; mi = i1; }
#pragma unroll
        for (int off = 32; off > 0; off >>= 1) {
            float ov = __shfl_xor(mv, off, 64);
            int   oi = __shfl_xor(mi, off, 64);
            if (ov > mv || (ov == mv && oi < mi)) { mv = ov; mi = oi; }
        }
        if (mi == i0)      { sel0 = true; v0 = -INFINITY; }
        else if (mi == i1) { sel1 = true; v1 = -INFINITY; }
    }
    if (i0 < PAIRS) scale[b * PAIRS + i0] = sel0 ? s0 : 0.0f;
    if (i1 < PAIRS) scale[b * PAIRS + i1] = sel1 ? s1 : 0.0f;
}

// K3: out[row] = (pooled[row]*scale[row]) @ w_fc + b_fc, grid-stride over
// rows (~10 rows/block). b_fc held in registers; zero-scale rows (80/90) are
// a single register-sourced float4 store. scale branch is block-uniform.
__global__ __launch_bounds__(256) void fc_kernel(
    const float* __restrict__ pooled, const float* __restrict__ scale,
    const float* __restrict__ w_fc, const float* __restrict__ b_fc,
    float* __restrict__ out)
{
    const int t = threadIdx.x;
    const float4 bb = ((const float4*)b_fc)[t];
    const float4* __restrict__ w4 = (const float4*)w_fc;
    __shared__ float sp[64];
    for (int row = blockIdx.x; row < NPAIR; row += gridDim.x) {
        const float s = scale[row];              // block-uniform
        float4* __restrict__ o = (float4*)(out + (size_t)row * CV);
        if (s == 0.0f) { o[t] = bb; continue; }
        __syncthreads();                         // prior sp reads done
        if (t < 64) sp[t] = pooled[(size_t)row * 64 + t] * s;
        __syncthreads();
        float4 acc = bb;
#pragma unroll 8
        for (int i = 0; i < 64; ++i) {
            const float c = sp[i];
            const float4 ww = w4[i * 256 + t];
            acc.x = fmaf(c, ww.x, acc.x);
            acc.y = fmaf(c, ww.y, acc.y);
            acc.z = fmaf(c, ww.z, acc.z);
            acc.w = fmaf(c, ww.w, acc.w);
        }
        o[t] = acc;
    }
}

extern "C" void kernel_launch(void* const* d_in, const int* in_sizes, int n_in,
                              void* d_out, int out_size, void* d_ws, size_t ws_size,
                              hipStream_t stream) {
    const float* feat  = (const float*)d_in[0];
    const float* w_att = (const float*)d_in[1];
    const float* b_att = (const float*)d_in[2];
    const float* w_fc  = (const float*)d_in[3];
    const float* b_fc  = (const float*)d_in[4];
    const int*   kp    = (const int*)d_in[5];
    float* out = (float*)d_out;

    float* pooled = (float*)d_ws;                     // NPAIR*64 floats (5.9 MB)
    float* scores = pooled + (size_t)NPAIR * 64;      // NPAIR floats
    float* scale  = scores + NPAIR;                   // NPAIR floats

    hipLaunchKernelGGL(pool_score_kernel, dim3(NPAIR), dim3(256), 0, stream,
                       feat, w_att, b_att, pooled, scores);
    hipLaunchKernelGGL(topk_kernel, dim3(BATCH), dim3(64), 0, stream,
                       scores, kp, scale);
    hipLaunchKernelGGL(fc_kernel, dim3(2304), dim3(256), 0, stream,
                       pooled, scale, w_fc, b_fc, out);
}